// Round 6
// baseline (252.463 us; speedup 1.0000x reference)
//
#include <hip/hip_runtime.h>

#define B_ROWS 16384
#define D_IN   1024
#define H_DIM  256
#define N_EXP  8
#define N_TASK 4
#define NKT    16   // K-tiles of 64 in D_IN

typedef short bf16x8 __attribute__((ext_vector_type(8)));
typedef float f32x4  __attribute__((ext_vector_type(4)));
typedef unsigned short u16x8 __attribute__((ext_vector_type(8)));

static __device__ __forceinline__ unsigned short f2bf(float f) {
  unsigned int u = __float_as_uint(f);
  u += 0x7fffu + ((u >> 16) & 1u);   // RNE
  return (unsigned short)(u >> 16);
}

// workspace layout (bytes)
#define WS_XB   0u          // ushort[16384*1024]  = 33,554,432 B
#define WS_WET  33554432u   // ushort[8*256*1024]  =  4,194,304 B
#define WS_WGT  37748736u   // ushort[32*1024]     =     65,536 B

// ---------------------------------------------------------------------------
// Kernel 1: prep. blocks [0,512): We cast+transpose -> We_t[e][h][k].
// blocks [512,544): Wg -> Wg_t[n][k]. blocks [544,8736): x fp32 -> x_b bf16.
// ---------------------------------------------------------------------------
__global__ void k_prep_w(const float* __restrict__ x, const float* __restrict__ We,
                         const float* __restrict__ Wg,
                         unsigned short* __restrict__ x_b,
                         unsigned short* __restrict__ We_t, unsigned short* __restrict__ Wg_t) {
  int bid = blockIdx.x;
  int t = threadIdx.x;
  if (bid < 512) {
    // one 64x64 tile of We[e]: [k][h] -> [h][k]
    int e = bid >> 6;
    int tl = bid & 63;
    int k0 = (tl >> 2) * 64, h0 = (tl & 3) * 64;
    __shared__ unsigned short tile[64][72];   // [h][k], padded
    const float* src = We + (size_t)e * (D_IN * H_DIM);
#pragma unroll
    for (int i = 0; i < 4; ++i) {
      int kk = (t >> 4) + i * 16;
      int hh = (t & 15) * 4;
      float4 v = *(const float4*)(src + (size_t)(k0 + kk) * H_DIM + h0 + hh);
      tile[hh + 0][kk] = f2bf(v.x);
      tile[hh + 1][kk] = f2bf(v.y);
      tile[hh + 2][kk] = f2bf(v.z);
      tile[hh + 3][kk] = f2bf(v.w);
    }
    __syncthreads();
    unsigned short* dst = We_t + (size_t)e * (H_DIM * D_IN);
#pragma unroll
    for (int i = 0; i < 4; ++i) {
      int hh = (t >> 4) + i * 16;
      int kk = (t & 15) * 4;
      ushort4 u = *(const ushort4*)&tile[hh][kk];
      *(ushort4*)(dst + (size_t)(h0 + hh) * D_IN + k0 + kk) = u;
    }
  } else if (bid < 544) {
    // Wg[4][1024][8] -> Wg_t[n][k], one n per block, 4 k per thread
    int n = bid - 512;               // 0..31
    int tsk = n >> 3, e = n & 7;
    int k = t * 4;
    const float* src = Wg + (size_t)tsk * (D_IN * 8) + e;
    ushort4 u;
    u.x = f2bf(src[(size_t)(k + 0) * 8]);
    u.y = f2bf(src[(size_t)(k + 1) * 8]);
    u.z = f2bf(src[(size_t)(k + 2) * 8]);
    u.w = f2bf(src[(size_t)(k + 3) * 8]);
    *(ushort4*)(Wg_t + (size_t)n * D_IN + k) = u;
  } else {
    // x cast: 8192 blocks x 256 thr x 8 elems
    size_t base = (size_t)(bid - 544) * 2048 + (size_t)t * 8;
    float4 v0 = *(const float4*)(x + base);
    float4 v1 = *(const float4*)(x + base + 4);
    u16x8 u;
    u[0] = f2bf(v0.x); u[1] = f2bf(v0.y);
    u[2] = f2bf(v0.z); u[3] = f2bf(v0.w);
    u[4] = f2bf(v1.x); u[5] = f2bf(v1.y);
    u[6] = f2bf(v1.z); u[7] = f2bf(v1.w);
    *(u16x8*)(x_b + base) = u;
  }
}

// ---------------------------------------------------------------------------
// Kernel 2: expert GEMM + FUSED gates + FUSED gated combine.
// 256x256 tile, 8 waves, BK=64, 4-phase pipelined K-loop (T3+T4),
// XOR-swizzle (T2), setprio (T5), XCD swizzle (T1).
//
// Gates pre-pass (before prologue): wave w computes logits for rows
// m0+w*32..+32 x 32 gate-cols via MFMA on x_b/Wg_t global reads (L2-shared
// across the 8 blocks of each m-tile), shfl-softmax in-register; 16 probs
// ride in VGPRs through the K-loop (all pre-pass loads consumed before the
// prologue, so the counted-vmcnt discipline is untouched). After the loop
// probs -> Gl LDS (reusing dead As), epilogue as R5.
// ---------------------------------------------------------------------------
__global__ __launch_bounds__(512, 2) void k_expert(const unsigned short* __restrict__ x_b,
                                                   const unsigned short* __restrict__ We_t,
                                                   const unsigned short* __restrict__ Wg_t,
                                                   const float* __restrict__ be,
                                                   const float* __restrict__ bg,
                                                   float* __restrict__ out) {
  __shared__ unsigned short As[2][256 * 64];   // 64 KiB
  __shared__ unsigned short Bs[2][256 * 64];   // 64 KiB
  int bid = blockIdx.x;
  int t = threadIdx.x;

  // XCD swizzle: 8 consecutive same-XCD slots share one m-tile's A panel
  int xcd = bid & 7;
  int idx = bid >> 3;              // 0..63
  int m   = xcd * 8 + (idx >> 3);  // m-tile 0..63
  int hs  = idx & 7;               // h-slice 0..7 (32 cols per expert)
  int m0  = m * 256;

  int w  = t >> 6, l = t & 63;
  int wm = w >> 2, wn = w & 3;     // wave tile: rows wm*128..+128, cols wn*64..+64
  int lr = l & 15, lq = l >> 4;

  const unsigned short* Ab = x_b + (size_t)m0 * D_IN;

  // ---- gates pre-pass: rows m0 + w*32 .. +32, 32 gate cols, full K ----
  f32x4 ga[2][2];   // [rg][colgrp]; lane holds col (cg*16+lr), rows w*32+rg*16+lq*4+j
#pragma unroll
  for (int rg = 0; rg < 2; ++rg)
#pragma unroll
    for (int cg = 0; cg < 2; ++cg) ga[rg][cg] = (f32x4){0.f, 0.f, 0.f, 0.f};
  {
    const unsigned short* xg0 = Ab + (size_t)(w * 32 + lr) * D_IN;
    const unsigned short* xg1 = Ab + (size_t)(w * 32 + 16 + lr) * D_IN;
    const unsigned short* wg0 = Wg_t + (size_t)lr * D_IN;
    const unsigned short* wg1 = Wg_t + (size_t)(16 + lr) * D_IN;
#pragma unroll 4
    for (int ko = 0; ko < 32; ++ko) {
      int k = ko * 32 + lq * 8;
      bf16x8 a0 = *(const bf16x8*)(xg0 + k);
      bf16x8 a1 = *(const bf16x8*)(xg1 + k);
      bf16x8 b0 = *(const bf16x8*)(wg0 + k);
      bf16x8 b1 = *(const bf16x8*)(wg1 + k);
      ga[0][0] = __builtin_amdgcn_mfma_f32_16x16x32_bf16(a0, b0, ga[0][0], 0, 0, 0);
      ga[0][1] = __builtin_amdgcn_mfma_f32_16x16x32_bf16(a0, b1, ga[0][1], 0, 0, 0);
      ga[1][0] = __builtin_amdgcn_mfma_f32_16x16x32_bf16(a1, b0, ga[1][0], 0, 0, 0);
      ga[1][1] = __builtin_amdgcn_mfma_f32_16x16x32_bf16(a1, b1, ga[1][1], 0, 0, 0);
    }
    // softmax over experts (col&7): lanes differing in lr bits 0..2
    float bga = bg[lr], bgb = bg[16 + lr];
#pragma unroll
    for (int rg = 0; rg < 2; ++rg) {
#pragma unroll
      for (int j = 0; j < 4; ++j) {
        float va = ga[rg][0][j] + bga;
        float vb = ga[rg][1][j] + bgb;
        float mxa = va, mxb = vb;
#pragma unroll
        for (int d = 1; d < 8; d <<= 1) {
          mxa = fmaxf(mxa, __shfl_xor(mxa, d));
          mxb = fmaxf(mxb, __shfl_xor(mxb, d));
        }
        va = __expf(va - mxa); vb = __expf(vb - mxb);
        float sa = va, sb = vb;
#pragma unroll
        for (int d = 1; d < 8; d <<= 1) {
          sa += __shfl_xor(sa, d);
          sb += __shfl_xor(sb, d);
        }
        ga[rg][0][j] = va / sa;
        ga[rg][1][j] = vb / sb;
      }
    }
  }

  const int sr = t >> 3, sg = t & 7;                 // staging row / 16B granule
  const int swz0 = ((lq ^ (lr & 7)) << 3);           // ks=0 swizzled granule (ushorts)
  const int swz1 = (((4 + lq) ^ (lr & 7)) << 3);     // ks=1
  const int arow0 = (wm * 128 + lr) << 6;            // + fm*1024
  const int brow0 = (wn * 64 + lr) << 6;             // + fn*1024

  // B global source rows for the 4 LDS rows this thread stages
  // (expert-interleaved mapping), swizzle pre-applied to source granule.
  size_t bsrc[4];
#pragma unroll
  for (int q2 = 0; q2 < 4; ++q2) {
    int rq = q2 * 64 + sr;                       // LDS row 0..255
    int me = (rq >> 3) & 7;
    int mh = hs * 32 + ((rq >> 6) & 3) * 8 + (rq & 7);
    bsrc[q2] = (size_t)(me * H_DIM + mh) * D_IN + (size_t)((sg ^ (rq & 7)) << 3);
  }

  f32x4 acc[8][4];
#pragma unroll
  for (int i = 0; i < 8; ++i)
#pragma unroll
    for (int j = 0; j < 4; ++j) acc[i][j] = (f32x4){0.f, 0.f, 0.f, 0.f};

#define STAGE_A(cb, kt, h)                                                                       \
  do {                                                                                           \
    int r0_ = (h) * 128 + sr;                                                                    \
    int r1_ = r0_ + 64;                                                                          \
    __builtin_amdgcn_global_load_lds(                                                            \
        (const __attribute__((address_space(1))) void*)(Ab + (size_t)r0_ * D_IN + (kt) * 64 +    \
                                                        ((sg ^ (r0_ & 7)) << 3)),                \
        (__attribute__((address_space(3))) void*)(&As[(cb)][r0_ * 64 + sg * 8]), 16, 0, 0);      \
    __builtin_amdgcn_global_load_lds(                                                            \
        (const __attribute__((address_space(1))) void*)(Ab + (size_t)r1_ * D_IN + (kt) * 64 +    \
                                                        ((sg ^ (r1_ & 7)) << 3)),                \
        (__attribute__((address_space(3))) void*)(&As[(cb)][r1_ * 64 + sg * 8]), 16, 0, 0);      \
  } while (0)
#define STAGE_B(cb, kt, h)                                                                       \
  do {                                                                                           \
    int r0_ = (h) * 128 + sr;                                                                    \
    int r1_ = r0_ + 64;                                                                          \
    __builtin_amdgcn_global_load_lds(                                                            \
        (const __attribute__((address_space(1))) void*)(We_t + bsrc[2 * (h)] + (kt) * 64),       \
        (__attribute__((address_space(3))) void*)(&Bs[(cb)][r0_ * 64 + sg * 8]), 16, 0, 0);      \
    __builtin_amdgcn_global_load_lds(                                                            \
        (const __attribute__((address_space(1))) void*)(We_t + bsrc[2 * (h) + 1] + (kt) * 64),   \
        (__attribute__((address_space(3))) void*)(&Bs[(cb)][r1_ * 64 + sg * 8]), 16, 0, 0);      \
  } while (0)

  // prologue: K-tile 0 fully + B of K-tile 1 (12 loads; newest 4 = B(1))
  // (all gates pre-pass loads already consumed -> vmcnt counts only these)
  STAGE_A(0, 0, 0); STAGE_A(0, 0, 1);
  STAGE_B(0, 0, 0); STAGE_B(0, 0, 1);
  STAGE_B(1, 1, 0); STAGE_B(1, 1, 1);
  asm volatile("s_waitcnt vmcnt(4)" ::: "memory");
  __builtin_amdgcn_s_barrier();

#pragma unroll 2
  for (int kt = 0; kt < NKT; ++kt) {
    int c = kt & 1;
    const unsigned short* Ap = &As[c][0];
    const unsigned short* Bp = &Bs[c][0];
    bf16x8 b0[4], b1[4];
#pragma unroll
    for (int q = 0; q < 4; ++q) {
      if (q == 0) {
#pragma unroll
        for (int fn = 0; fn < 4; ++fn) {
          b0[fn] = *(const bf16x8*)(Bp + brow0 + fn * 1024 + swz0);
          b1[fn] = *(const bf16x8*)(Bp + brow0 + fn * 1024 + swz1);
        }
      }
      bf16x8 a00 = *(const bf16x8*)(Ap + arow0 + (2 * q) * 1024 + swz0);
      bf16x8 a01 = *(const bf16x8*)(Ap + arow0 + (2 * q) * 1024 + swz1);
      bf16x8 a10 = *(const bf16x8*)(Ap + arow0 + (2 * q + 1) * 1024 + swz0);
      bf16x8 a11 = *(const bf16x8*)(Ap + arow0 + (2 * q + 1) * 1024 + swz1);
      if (q == 0)      { if (kt + 1 < NKT) STAGE_A(c ^ 1, kt + 1, 0); }
      else if (q == 1) { if (kt + 1 < NKT) STAGE_A(c ^ 1, kt + 1, 1); }
      else if (q == 2) { if (kt + 2 < NKT) STAGE_B(c, kt + 2, 0); }
      else             { if (kt + 2 < NKT) STAGE_B(c, kt + 2, 1); }
      __builtin_amdgcn_s_barrier();
      asm volatile("s_waitcnt lgkmcnt(0)" ::: "memory");
      __builtin_amdgcn_s_setprio(1);
#pragma unroll
      for (int fn = 0; fn < 4; ++fn) {
        acc[2 * q][fn]     = __builtin_amdgcn_mfma_f32_16x16x32_bf16(a00, b0[fn], acc[2 * q][fn], 0, 0, 0);
        acc[2 * q][fn]     = __builtin_amdgcn_mfma_f32_16x16x32_bf16(a01, b1[fn], acc[2 * q][fn], 0, 0, 0);
        acc[2 * q + 1][fn] = __builtin_amdgcn_mfma_f32_16x16x32_bf16(a10, b0[fn], acc[2 * q + 1][fn], 0, 0, 0);
        acc[2 * q + 1][fn] = __builtin_amdgcn_mfma_f32_16x16x32_bf16(a11, b1[fn], acc[2 * q + 1][fn], 0, 0, 0);
      }
      __builtin_amdgcn_s_setprio(0);
      if (q == 3) {
        if (kt < NKT - 2)        asm volatile("s_waitcnt vmcnt(4)" ::: "memory");
        else if (kt == NKT - 2)  asm volatile("s_waitcnt vmcnt(0)" ::: "memory");
      }
      __builtin_amdgcn_s_barrier();
    }
  }
#undef STAGE_A
#undef STAGE_B

  // ---- write gate probs (registers) into LDS Gl, reusing dead As ----
  float (*Gl)[260] = (float (*)[260])(&As[0][0]);   // 32x260 f32 = 33.3 KB
#pragma unroll
  for (int rg = 0; rg < 2; ++rg)
#pragma unroll
    for (int j = 0; j < 4; ++j) {
      int rloc = w * 32 + rg * 16 + lq * 4 + j;
      Gl[lr][rloc]      = ga[rg][0][j];
      Gl[16 + lr][rloc] = ga[rg][1][j];
    }
  __syncthreads();

  // epilogue: bias + relu + gated expert-sum + direct towers write.
  // lane col n(fn) = wn*64+fn*16+lr -> e = 2*fn+hi, h = hs*32+wn*8+(lr&7)
  // paired exchange: one shfl_xor(8) serves both hi-halves' task-pair.
  int hi = lr >> 3, h7 = lr & 7;
  int hglob = hs * 32 + wn * 8 + h7;
  float bev[4];
#pragma unroll
  for (int fn = 0; fn < 4; ++fn)
    bev[fn] = be[(2 * fn + hi) * H_DIM + hglob];
#pragma unroll
  for (int fm = 0; fm < 8; ++fm) {
    int rloc = wm * 128 + fm * 16 + lq * 4;
    int r0 = m0 + rloc;
    float vv[4][4];
#pragma unroll
    for (int fn = 0; fn < 4; ++fn)
#pragma unroll
      for (int j = 0; j < 4; ++j)
        vv[fn][j] = fmaxf(acc[fm][fn][j] + bev[fn], 0.f);
    float p[4][4];
#pragma unroll
    for (int tk = 0; tk < 4; ++tk) {
      f32x4 gv[4];
#pragma unroll
      for (int fn = 0; fn < 4; ++fn)
        gv[fn] = *(const f32x4*)&Gl[tk * 8 + 2 * fn + hi][rloc];
#pragma unroll
      for (int j = 0; j < 4; ++j)
        p[tk][j] = gv[0][j] * vv[0][j] + gv[1][j] * vv[1][j] +
                   gv[2][j] * vv[2][j] + gv[3][j] * vv[3][j];
    }
#pragma unroll
    for (int j = 0; j < 4; ++j) {
      float sa = hi ? p[0][j] : p[2][j];   // send partner-half's even task
      float sb = hi ? p[1][j] : p[3][j];   // send partner-half's odd task
      float ra = __shfl_xor(sa, 8);
      float rb = __shfl_xor(sb, 8);
      float t0 = (hi ? p[2][j] : p[0][j]) + ra;   // own even task total
      float t1 = (hi ? p[3][j] : p[1][j]) + rb;   // own odd task total
      size_t tk0 = (size_t)(hi * 2);
      out[(tk0 * B_ROWS + r0 + j) * H_DIM + hglob]       = t0;
      out[((tk0 + 1) * B_ROWS + r0 + j) * H_DIM + hglob] = t1;
    }
  }
}

extern "C" void kernel_launch(void* const* d_in, const int* in_sizes, int n_in,
                              void* d_out, int out_size, void* d_ws, size_t ws_size,
                              hipStream_t stream) {
  const float* x  = (const float*)d_in[0];
  const float* We = (const float*)d_in[1];
  const float* be = (const float*)d_in[2];
  const float* Wg = (const float*)d_in[3];
  const float* bg = (const float*)d_in[4];
  float* out = (float*)d_out;
  char* ws = (char*)d_ws;
  unsigned short* x_b  = (unsigned short*)(ws + WS_XB);
  unsigned short* We_t = (unsigned short*)(ws + WS_WET);
  unsigned short* Wg_t = (unsigned short*)(ws + WS_WGT);

  k_prep_w<<<544 + 8192, 256, 0, stream>>>(x, We, Wg, x_b, We_t, Wg_t);
  k_expert<<<512, 512, 0, stream>>>(x_b, We_t, Wg_t, be, bg, out);
}

// Round 7
// 199.104 us; speedup vs baseline: 1.2680x; 1.2680x over previous
//
#include <hip/hip_runtime.h>

#define B_ROWS 16384
#define D_IN   1024
#define H_DIM  256
#define N_EXP  8
#define N_TASK 4
#define NKT    16   // K-tiles of 64 in D_IN

typedef short bf16x8 __attribute__((ext_vector_type(8)));
typedef float f32x4  __attribute__((ext_vector_type(4)));
typedef unsigned short u16x8 __attribute__((ext_vector_type(8)));

static __device__ __forceinline__ unsigned short f2bf(float f) {
  unsigned int u = __float_as_uint(f);
  u += 0x7fffu + ((u >> 16) & 1u);   // RNE
  return (unsigned short)(u >> 16);
}

// workspace layout (bytes)
#define WS_XB   0u          // ushort[16384*1024]  = 33,554,432 B
#define WS_WET  33554432u   // ushort[8*256*1024]  =  4,194,304 B
#define WS_GT   37814272u   // float [32*16384]    =  2,097,152 B (transposed probs Gt[t*8+e][row])

// ---------------------------------------------------------------------------
// Kernel 1: merged prep + gates (removes one launch boundary).
// blocks [0,512): We cast+transpose -> We_t[e][h][k].
// blocks [512,1536): gates for 16 rows each: stage Wg fp32->bf16 LDS
// (self-sufficient, no Wg_t dependency), fused x-cast (x fp32 -> x_b bf16
// side effect), MFMA logits, shfl softmax -> Gt[t*8+e][row].
// ---------------------------------------------------------------------------
__global__ __launch_bounds__(256) void k_prep_gates(const float* __restrict__ x,
                                                    const float* __restrict__ We,
                                                    const float* __restrict__ Wg,
                                                    unsigned short* __restrict__ x_b,
                                                    unsigned short* __restrict__ We_t,
                                                    const float* __restrict__ bg,
                                                    float* __restrict__ Gt) {
  __shared__ char smem[75264];   // union: We-tile (9216B) | wgs 66048B + red 9216B
  int bid = blockIdx.x;
  int t = threadIdx.x;

  if (bid < 512) {
    // ---- one 64x64 tile of We[e]: [k][h] -> [h][k] ----
    unsigned short (*tile)[72] = (unsigned short (*)[72])smem;   // [64][72] padded
    int e = bid >> 6;
    int tl = bid & 63;
    int k0 = (tl >> 2) * 64, h0 = (tl & 3) * 64;
    const float* src = We + (size_t)e * (D_IN * H_DIM);
#pragma unroll
    for (int i = 0; i < 4; ++i) {
      int kk = (t >> 4) + i * 16;
      int hh = (t & 15) * 4;
      float4 v = *(const float4*)(src + (size_t)(k0 + kk) * H_DIM + h0 + hh);
      tile[hh + 0][kk] = f2bf(v.x);
      tile[hh + 1][kk] = f2bf(v.y);
      tile[hh + 2][kk] = f2bf(v.z);
      tile[hh + 3][kk] = f2bf(v.w);
    }
    __syncthreads();
    unsigned short* dst = We_t + (size_t)e * (H_DIM * D_IN);
#pragma unroll
    for (int i = 0; i < 4; ++i) {
      int hh = (t >> 4) + i * 16;
      int kk = (t & 15) * 4;
      ushort4 u = *(const ushort4*)&tile[hh][kk];
      *(ushort4*)(dst + (size_t)(h0 + hh) * D_IN + k0 + kk) = u;
    }
    return;
  }

  // ---- gates ----
  unsigned short* wgs = (unsigned short*)smem;                  // [32][1032] bf16
  float (*red)[16][36] = (float (*)[16][36])(smem + 66048);     // [4][16][36]
  int m0 = (bid - 512) * 16;

  // stage Wg[4][1024][8] fp32 -> wgs[n=tsk*8+e][k] bf16.
  // idx = t*4 + i*1024: per-instr lanes read contiguous 1KB; LDS writes
  // spread (4n + kk/2) across all 32 banks (<=2-way).
#pragma unroll
  for (int i = 0; i < 32; ++i) {
    int idx = t * 4 + i * 1024;
    float4 v = *(const float4*)(Wg + idx);
    int kk = (idx >> 3) & 1023;
    int nb = ((idx >> 13) << 3) + (idx & 7);
    wgs[(size_t)(nb + 0) * 1032 + kk] = f2bf(v.x);
    wgs[(size_t)(nb + 1) * 1032 + kk] = f2bf(v.y);
    wgs[(size_t)(nb + 2) * 1032 + kk] = f2bf(v.z);
    wgs[(size_t)(nb + 3) * 1032 + kk] = f2bf(v.w);
  }
  __syncthreads();

  int w = t >> 6, l = t & 63;
  int lr = l & 15, lq = l >> 4;
  int kbase = w * 256;
  f32x4 acc0 = {0.f, 0.f, 0.f, 0.f}, acc1 = {0.f, 0.f, 0.f, 0.f};

  const float* xrow = x + (size_t)(m0 + lr) * D_IN;
  unsigned short* xbrow = x_b + (size_t)(m0 + lr) * D_IN;
  const unsigned short* wg0 = wgs + (size_t)lr * 1032;
  const unsigned short* wg1 = wgs + (size_t)(16 + lr) * 1032;

#pragma unroll
  for (int ks = 0; ks < 8; ++ks) {
    int k = kbase + ks * 32 + lq * 8;
    float4 v0 = *(const float4*)(xrow + k);
    float4 v1 = *(const float4*)(xrow + k + 4);
    bf16x8 a;
    a[0] = (short)f2bf(v0.x); a[1] = (short)f2bf(v0.y);
    a[2] = (short)f2bf(v0.z); a[3] = (short)f2bf(v0.w);
    a[4] = (short)f2bf(v1.x); a[5] = (short)f2bf(v1.y);
    a[6] = (short)f2bf(v1.z); a[7] = (short)f2bf(v1.w);
    *(bf16x8*)(xbrow + k) = a;
    bf16x8 b0 = *(const bf16x8*)(wg0 + k);
    bf16x8 b1 = *(const bf16x8*)(wg1 + k);
    acc0 = __builtin_amdgcn_mfma_f32_16x16x32_bf16(a, b0, acc0, 0, 0, 0);
    acc1 = __builtin_amdgcn_mfma_f32_16x16x32_bf16(a, b1, acc1, 0, 0, 0);
  }

  // cross-wave K-reduce
#pragma unroll
  for (int j = 0; j < 4; ++j) {
    red[w][lq * 4 + j][lr]      = acc0[j];
    red[w][lq * 4 + j][16 + lr] = acc1[j];
  }
  __syncthreads();
  if (w == 0) {
#pragma unroll
    for (int j = 0; j < 4; ++j) {
      int rr = lq * 4 + j;
      acc0[j] = red[0][rr][lr] + red[1][rr][lr] + red[2][rr][lr] + red[3][rr][lr];
      acc1[j] = red[0][rr][16 + lr] + red[1][rr][16 + lr] + red[2][rr][16 + lr] + red[3][rr][16 + lr];
    }
    // softmax over e (lanes differing in bits 0..2); colb = lr
    int colb = lr;
    int rbase = m0 + lq * 4;
    float bga = bg[colb], bgb = bg[16 + colb];
#pragma unroll
    for (int j = 0; j < 4; ++j) {
      float va = acc0[j] + bga;
      float vb = acc1[j] + bgb;
      float mxa = va, mxb = vb;
#pragma unroll
      for (int d = 1; d < 8; d <<= 1) {
        mxa = fmaxf(mxa, __shfl_xor(mxa, d));
        mxb = fmaxf(mxb, __shfl_xor(mxb, d));
      }
      va = __expf(va - mxa); vb = __expf(vb - mxb);
      float sa = va, sb = vb;
#pragma unroll
      for (int d = 1; d < 8; d <<= 1) {
        sa += __shfl_xor(sa, d);
        sb += __shfl_xor(sb, d);
      }
      va /= sa; vb /= sb;
      Gt[(size_t)colb * B_ROWS + rbase + j]        = va;
      Gt[(size_t)(16 + colb) * B_ROWS + rbase + j] = vb;
    }
  }
}

// ---------------------------------------------------------------------------
// Kernel 2: expert GEMM + FUSED gated combine (VERBATIM R5 — the verified
// 86.9 µs build). 256x256 tile, 8 waves, BK=64, 4-phase pipelined K-loop
// (T3+T4), XOR-swizzle (T2), setprio (T5), XCD swizzle (T1). Epilogue
// gates staged once into LDS (reusing dead As).
// ---------------------------------------------------------------------------
__global__ __launch_bounds__(512, 2) void k_expert(const unsigned short* __restrict__ x_b,
                                                   const unsigned short* __restrict__ We_t,
                                                   const float* __restrict__ be,
                                                   const float* __restrict__ Gt,
                                                   float* __restrict__ out) {
  __shared__ unsigned short As[2][256 * 64];   // 64 KiB
  __shared__ unsigned short Bs[2][256 * 64];   // 64 KiB
  int bid = blockIdx.x;
  int t = threadIdx.x;

  // XCD swizzle: 8 consecutive same-XCD slots share one m-tile's A panel
  int xcd = bid & 7;
  int idx = bid >> 3;              // 0..63
  int m   = xcd * 8 + (idx >> 3);  // m-tile 0..63
  int hs  = idx & 7;               // h-slice 0..7 (32 cols per expert)
  int m0  = m * 256;

  int w  = t >> 6, l = t & 63;
  int wm = w >> 2, wn = w & 3;     // wave tile: rows wm*128..+128, cols wn*64..+64
  int lr = l & 15, lq = l >> 4;

  const unsigned short* Ab = x_b + (size_t)m0 * D_IN;

  const int sr = t >> 3, sg = t & 7;                 // staging row / 16B granule
  const int swz0 = ((lq ^ (lr & 7)) << 3);           // ks=0 swizzled granule (ushorts)
  const int swz1 = (((4 + lq) ^ (lr & 7)) << 3);     // ks=1
  const int arow0 = (wm * 128 + lr) << 6;            // + fm*1024
  const int brow0 = (wn * 64 + lr) << 6;             // + fn*1024

  // B global source rows for the 4 LDS rows this thread stages
  // (expert-interleaved mapping), swizzle pre-applied to source granule.
  size_t bsrc[4];
#pragma unroll
  for (int q2 = 0; q2 < 4; ++q2) {
    int rq = q2 * 64 + sr;                       // LDS row 0..255
    int me = (rq >> 3) & 7;
    int mh = hs * 32 + ((rq >> 6) & 3) * 8 + (rq & 7);
    bsrc[q2] = (size_t)(me * H_DIM + mh) * D_IN + (size_t)((sg ^ (rq & 7)) << 3);
  }

  f32x4 acc[8][4];
#pragma unroll
  for (int i = 0; i < 8; ++i)
#pragma unroll
    for (int j = 0; j < 4; ++j) acc[i][j] = (f32x4){0.f, 0.f, 0.f, 0.f};

#define STAGE_A(cb, kt, h)                                                                       \
  do {                                                                                           \
    int r0_ = (h) * 128 + sr;                                                                    \
    int r1_ = r0_ + 64;                                                                          \
    __builtin_amdgcn_global_load_lds(                                                            \
        (const __attribute__((address_space(1))) void*)(Ab + (size_t)r0_ * D_IN + (kt) * 64 +    \
                                                        ((sg ^ (r0_ & 7)) << 3)),                \
        (__attribute__((address_space(3))) void*)(&As[(cb)][r0_ * 64 + sg * 8]), 16, 0, 0);      \
    __builtin_amdgcn_global_load_lds(                                                            \
        (const __attribute__((address_space(1))) void*)(Ab + (size_t)r1_ * D_IN + (kt) * 64 +    \
                                                        ((sg ^ (r1_ & 7)) << 3)),                \
        (__attribute__((address_space(3))) void*)(&As[(cb)][r1_ * 64 + sg * 8]), 16, 0, 0);      \
  } while (0)
#define STAGE_B(cb, kt, h)                                                                       \
  do {                                                                                           \
    int r0_ = (h) * 128 + sr;                                                                    \
    int r1_ = r0_ + 64;                                                                          \
    __builtin_amdgcn_global_load_lds(                                                            \
        (const __attribute__((address_space(1))) void*)(We_t + bsrc[2 * (h)] + (kt) * 64),       \
        (__attribute__((address_space(3))) void*)(&Bs[(cb)][r0_ * 64 + sg * 8]), 16, 0, 0);      \
    __builtin_amdgcn_global_load_lds(                                                            \
        (const __attribute__((address_space(1))) void*)(We_t + bsrc[2 * (h) + 1] + (kt) * 64),   \
        (__attribute__((address_space(3))) void*)(&Bs[(cb)][r1_ * 64 + sg * 8]), 16, 0, 0);      \
  } while (0)

  // prologue: K-tile 0 fully + B of K-tile 1 (12 loads; newest 4 = B(1))
  STAGE_A(0, 0, 0); STAGE_A(0, 0, 1);
  STAGE_B(0, 0, 0); STAGE_B(0, 0, 1);
  STAGE_B(1, 1, 0); STAGE_B(1, 1, 1);
  asm volatile("s_waitcnt vmcnt(4)" ::: "memory");
  __builtin_amdgcn_s_barrier();

#pragma unroll 2
  for (int kt = 0; kt < NKT; ++kt) {
    int c = kt & 1;
    const unsigned short* Ap = &As[c][0];
    const unsigned short* Bp = &Bs[c][0];
    bf16x8 b0[4], b1[4];
#pragma unroll
    for (int q = 0; q < 4; ++q) {
      if (q == 0) {
#pragma unroll
        for (int fn = 0; fn < 4; ++fn) {
          b0[fn] = *(const bf16x8*)(Bp + brow0 + fn * 1024 + swz0);
          b1[fn] = *(const bf16x8*)(Bp + brow0 + fn * 1024 + swz1);
        }
      }
      bf16x8 a00 = *(const bf16x8*)(Ap + arow0 + (2 * q) * 1024 + swz0);
      bf16x8 a01 = *(const bf16x8*)(Ap + arow0 + (2 * q) * 1024 + swz1);
      bf16x8 a10 = *(const bf16x8*)(Ap + arow0 + (2 * q + 1) * 1024 + swz0);
      bf16x8 a11 = *(const bf16x8*)(Ap + arow0 + (2 * q + 1) * 1024 + swz1);
      if (q == 0)      { if (kt + 1 < NKT) STAGE_A(c ^ 1, kt + 1, 0); }
      else if (q == 1) { if (kt + 1 < NKT) STAGE_A(c ^ 1, kt + 1, 1); }
      else if (q == 2) { if (kt + 2 < NKT) STAGE_B(c, kt + 2, 0); }
      else             { if (kt + 2 < NKT) STAGE_B(c, kt + 2, 1); }
      __builtin_amdgcn_s_barrier();
      asm volatile("s_waitcnt lgkmcnt(0)" ::: "memory");
      __builtin_amdgcn_s_setprio(1);
#pragma unroll
      for (int fn = 0; fn < 4; ++fn) {
        acc[2 * q][fn]     = __builtin_amdgcn_mfma_f32_16x16x32_bf16(a00, b0[fn], acc[2 * q][fn], 0, 0, 0);
        acc[2 * q][fn]     = __builtin_amdgcn_mfma_f32_16x16x32_bf16(a01, b1[fn], acc[2 * q][fn], 0, 0, 0);
        acc[2 * q + 1][fn] = __builtin_amdgcn_mfma_f32_16x16x32_bf16(a10, b0[fn], acc[2 * q + 1][fn], 0, 0, 0);
        acc[2 * q + 1][fn] = __builtin_amdgcn_mfma_f32_16x16x32_bf16(a11, b1[fn], acc[2 * q + 1][fn], 0, 0, 0);
      }
      __builtin_amdgcn_s_setprio(0);
      if (q == 3) {
        if (kt < NKT - 2)        asm volatile("s_waitcnt vmcnt(4)" ::: "memory");
        else if (kt == NKT - 2)  asm volatile("s_waitcnt vmcnt(0)" ::: "memory");
      }
      __builtin_amdgcn_s_barrier();
    }
  }
#undef STAGE_A
#undef STAGE_B

  // ---- stage Gt slice (32 gate-cols x 256 rows) into LDS, reusing As ----
  float (*Gl)[260] = (float (*)[260])(&As[0][0]);   // 32x260 f32 = 33.3 KB
  {
    int n  = t >> 4;             // 0..31 gate-col
    int c0 = (t & 15) * 16;      // 0..240 row offset
    const float* gsrc = Gt + (size_t)n * B_ROWS + m0 + c0;
    f32x4 g0 = *(const f32x4*)(gsrc + 0);
    f32x4 g1 = *(const f32x4*)(gsrc + 4);
    f32x4 g2 = *(const f32x4*)(gsrc + 8);
    f32x4 g3 = *(const f32x4*)(gsrc + 12);
    *(f32x4*)&Gl[n][c0 + 0]  = g0;
    *(f32x4*)&Gl[n][c0 + 4]  = g1;
    *(f32x4*)&Gl[n][c0 + 8]  = g2;
    *(f32x4*)&Gl[n][c0 + 12] = g3;
  }
  __syncthreads();

  // epilogue: bias + relu + gated expert-sum + direct towers write.
  int hi = lr >> 3, h7 = lr & 7;
  int hglob = hs * 32 + wn * 8 + h7;
  float bev[4];
#pragma unroll
  for (int fn = 0; fn < 4; ++fn)
    bev[fn] = be[(2 * fn + hi) * H_DIM + hglob];
#pragma unroll
  for (int fm = 0; fm < 8; ++fm) {
    int rloc = wm * 128 + fm * 16 + lq * 4;
    int r0 = m0 + rloc;
    float vv[4][4];
#pragma unroll
    for (int fn = 0; fn < 4; ++fn)
#pragma unroll
      for (int j = 0; j < 4; ++j)
        vv[fn][j] = fmaxf(acc[fm][fn][j] + bev[fn], 0.f);
    float p[4][4];
#pragma unroll
    for (int tk = 0; tk < 4; ++tk) {
      f32x4 gv[4];
#pragma unroll
      for (int fn = 0; fn < 4; ++fn)
        gv[fn] = *(const f32x4*)&Gl[tk * 8 + 2 * fn + hi][rloc];
#pragma unroll
      for (int j = 0; j < 4; ++j)
        p[tk][j] = gv[0][j] * vv[0][j] + gv[1][j] * vv[1][j] +
                   gv[2][j] * vv[2][j] + gv[3][j] * vv[3][j];
    }
#pragma unroll
    for (int j = 0; j < 4; ++j) {
      float sa = hi ? p[0][j] : p[2][j];   // send partner-half's even task
      float sb = hi ? p[1][j] : p[3][j];   // send partner-half's odd task
      float ra = __shfl_xor(sa, 8);
      float rb = __shfl_xor(sb, 8);
      float t0 = (hi ? p[2][j] : p[0][j]) + ra;   // own even task total
      float t1 = (hi ? p[3][j] : p[1][j]) + rb;   // own odd task total
      size_t tk0 = (size_t)(hi * 2);
      out[(tk0 * B_ROWS + r0 + j) * H_DIM + hglob]       = t0;
      out[((tk0 + 1) * B_ROWS + r0 + j) * H_DIM + hglob] = t1;
    }
  }
}

extern "C" void kernel_launch(void* const* d_in, const int* in_sizes, int n_in,
                              void* d_out, int out_size, void* d_ws, size_t ws_size,
                              hipStream_t stream) {
  const float* x  = (const float*)d_in[0];
  const float* We = (const float*)d_in[1];
  const float* be = (const float*)d_in[2];
  const float* Wg = (const float*)d_in[3];
  const float* bg = (const float*)d_in[4];
  float* out = (float*)d_out;
  char* ws = (char*)d_ws;
  unsigned short* x_b  = (unsigned short*)(ws + WS_XB);
  unsigned short* We_t = (unsigned short*)(ws + WS_WET);
  float*          Gt   = (float*)(ws + WS_GT);

  k_prep_gates<<<1536, 256, 0, stream>>>(x, We, Wg, x_b, We_t, bg, Gt);
  k_expert<<<512, 512, 0, stream>>>(x_b, We_t, be, Gt, out);
}